// Round 4
// baseline (582.814 us; speedup 1.0000x reference)
//
#include <hip/hip_runtime.h>
#include <hip/hip_bf16.h>

#define D 128            // D_IN == D_OUT == 128
#define RPB 16           // rows per bucket
#define NBMAX 640        // max buckets (N<=10240)
#define EPB 8192         // edges per block in hist/place
#define NPW 4            // rows per wave in matvec phase
#define EPS 1e-8f

typedef unsigned int uint32;

__device__ __forceinline__ uint32 f2bf_rne(float f) {
    uint32 u = __float_as_uint(f);
    return (u + 0x7fffu + ((u >> 16) & 1u)) >> 16;   // round-nearest-even
}
__device__ __forceinline__ float bfl(uint32 u) { return __uint_as_float(u << 16); }
__device__ __forceinline__ float bfh(uint32 u) { return __uint_as_float(u & 0xffff0000u); }

// ---------------- prep: bf16-pack x ----------------

__global__ void k_prep(const float* __restrict__ x, uint32* __restrict__ xb, int NX) {
    int i = blockIdx.x * blockDim.x + threadIdx.x;
    if (i < NX) {
        float2 f = ((const float2*)x)[i];
        xb[i] = f2bf_rne(f.x) | (f2bf_rne(f.y) << 16);
    }
}

// ---------------- W transpose + bf16 pack ----------------

__global__ void k_wprep(const float* __restrict__ Wm, const float* __restrict__ Wu,
                        uint32* __restrict__ WTmb, uint32* __restrict__ WTub) {
    int i = blockIdx.x * blockDim.x + threadIdx.x;   // 64*128 threads
    if (i >= 64 * 128) return;
    int k2 = i >> 7, f = i & 127;
    WTmb[i] = f2bf_rne(Wm[f * D + 2 * k2]) | (f2bf_rne(Wm[f * D + 2 * k2 + 1]) << 16);
    WTub[i] = f2bf_rne(Wu[f * D + 2 * k2]) | (f2bf_rne(Wu[f * D + 2 * k2 + 1]) << 16);
}

// ---------------- bucket histogram (LDS pre-aggregated) ----------------

__global__ __launch_bounds__(256) void k_bhist(const int* __restrict__ ei,
                                               int* __restrict__ bhist, int E_, int NB) {
    __shared__ int h[NBMAX];
    for (int i = threadIdx.x; i < NB; i += 256) h[i] = 0;
    __syncthreads();
    int base = blockIdx.x * EPB;
    int hi = min(base + EPB, E_);
    for (int i = base + threadIdx.x; i < hi; i += 256)
        atomicAdd(&h[ei[i] >> 4], 1);
    __syncthreads();
    for (int i = threadIdx.x; i < NB; i += 256)
        if (h[i]) atomicAdd(&bhist[i], h[i]);
}

// ---------------- scan (generic exclusive scan -> starts) ----------------

__global__ void k_scan(const int* __restrict__ deg, int* __restrict__ starts, int N_) {
    __shared__ int part[1024];
    int t = threadIdx.x;
    int chunk = (N_ + 1023) / 1024;
    int s = t * chunk;
    int e = min(N_, s + chunk);
    int sum = 0;
    for (int i = s; i < e; ++i) sum += deg[i];
    part[t] = sum;
    __syncthreads();
    for (int off = 1; off < 1024; off <<= 1) {
        int u = (t >= off) ? part[t - off] : 0;
        __syncthreads();
        part[t] += u;
        __syncthreads();
    }
    int run = part[t] - sum;
    for (int i = s; i < e; ++i) { starts[i] = run; run += deg[i]; }
    if (t == 1023) starts[N_] = part[1023];
}

// ---------------- place: block-local counting sort by bucket, coalesced out ----

__global__ __launch_bounds__(256) void k_bplace(
        const int* __restrict__ ei, const int* __restrict__ bstart,
        int* __restrict__ bcur, uint32* __restrict__ eb, int E_, int NB) {
    __shared__ int h[NBMAX];      // local hist (counts)
    __shared__ int off[NBMAX];    // local exclusive start -> running cursor
    __shared__ int bias[NBMAX];   // global_base - local_start
    __shared__ uint32 stg[EPB];   // sorted staging (32 KB)

    const int tid = threadIdx.x;
    const int base = blockIdx.x * EPB;
    const int nE = min(EPB, E_ - base);

    for (int i = tid; i < NB; i += 256) h[i] = 0;
    __syncthreads();

    // pass 1: local histogram
    for (int i = tid; i < nE; i += 256)
        atomicAdd(&h[ei[base + i] >> 4], 1);
    __syncthreads();

    // exclusive scan of h -> off, by one wave (lane handles 10 bins)
    if (tid < 64) {
        int b0 = tid * 10;
        int loc[10];
        int lsum = 0;
        #pragma unroll
        for (int j = 0; j < 10; ++j) {
            int b = b0 + j;
            int v = (b < NB) ? h[b] : 0;
            loc[j] = lsum;
            lsum += v;
        }
        int run = lsum;
        #pragma unroll
        for (int o = 1; o < 64; o <<= 1) {
            int u = __shfl_up(run, o);
            if (tid >= o) run += u;
        }
        int excl = run - lsum;
        #pragma unroll
        for (int j = 0; j < 10; ++j) {
            int b = b0 + j;
            if (b < NB) off[b] = excl + loc[j];
        }
    }
    __syncthreads();

    // reserve global ranges per bucket
    for (int b = tid; b < NB; b += 256) {
        int c = h[b];
        if (c) {
            int g = atomicAdd(&bcur[b], c);
            bias[b] = (bstart[b] + g) - off[b];
        }
    }
    __syncthreads();

    // pass 2: scatter into sorted staging
    for (int i = tid; i < nE; i += 256) {
        int r = ei[base + i];
        int c = ei[E_ + base + i];
        int b = r >> 4;
        int p = atomicAdd(&off[b], 1);
        stg[p] = ((uint32)r << 16) | (uint32)c;
    }
    __syncthreads();

    // pass 3: linear write-out (coalesced runs per bucket)
    for (int i = tid; i < nE; i += 256) {
        uint32 v = stg[i];
        int b = v >> 20;               // (r>>16... r = v>>16, bucket = r>>4
        eb[bias[b] + i] = v;
    }
}

// ---------------- fused: bucket gather + 2x matvec + mean + norm ----------------
// one block per bucket (16 rows); 256 threads = 4 waves

__global__ __launch_bounds__(256) void k_fused(
        const uint32* __restrict__ xb, const int* __restrict__ bstart,
        const uint32* __restrict__ eb,
        const uint32* __restrict__ WTmb, const float* __restrict__ bm,
        const uint32* __restrict__ WTub, const float* __restrict__ bu,
        float* __restrict__ out, int N_) {
    __shared__ float acc[RPB][D];    // 8 KB aggregated sums
    __shared__ float o_lds[RPB][D];  // 8 KB intermediate
    __shared__ int degl[RPB];

    const int tid  = threadIdx.x;
    const int lane = tid & 63;
    const int wv   = tid >> 6;

    for (int i = tid; i < RPB * D; i += 256) ((float*)acc)[i] = 0.f;
    if (tid < RPB) degl[tid] = 0;
    __syncthreads();

    const int s = bstart[blockIdx.x];
    const int e = bstart[blockIdx.x + 1];

    // ---- gather: each wave takes 64-edge chunks, strided by 256 ----
    for (int ii = s + wv * 64; ii < e; ii += 256) {
        int m = min(64, e - ii);
        uint32 v_l = (lane < m) ? eb[ii + lane] : 0;
        if (lane < m) atomicAdd(&degl[(v_l >> 16) & 15], 1);
        int t = 0;
        for (; t + 8 <= m; t += 8) {
            uint32 e0 = __builtin_amdgcn_readlane(v_l, t + 0);
            uint32 e1 = __builtin_amdgcn_readlane(v_l, t + 1);
            uint32 e2 = __builtin_amdgcn_readlane(v_l, t + 2);
            uint32 e3 = __builtin_amdgcn_readlane(v_l, t + 3);
            uint32 e4 = __builtin_amdgcn_readlane(v_l, t + 4);
            uint32 e5 = __builtin_amdgcn_readlane(v_l, t + 5);
            uint32 e6 = __builtin_amdgcn_readlane(v_l, t + 6);
            uint32 e7 = __builtin_amdgcn_readlane(v_l, t + 7);
            uint32 v0 = xb[((e0 & 0xffffu) << 6) + lane];
            uint32 v1 = xb[((e1 & 0xffffu) << 6) + lane];
            uint32 v2 = xb[((e2 & 0xffffu) << 6) + lane];
            uint32 v3 = xb[((e3 & 0xffffu) << 6) + lane];
            uint32 v4 = xb[((e4 & 0xffffu) << 6) + lane];
            uint32 v5 = xb[((e5 & 0xffffu) << 6) + lane];
            uint32 v6 = xb[((e6 & 0xffffu) << 6) + lane];
            uint32 v7 = xb[((e7 & 0xffffu) << 6) + lane];
            int r0 = (e0 >> 16) & 15, r1 = (e1 >> 16) & 15;
            int r2 = (e2 >> 16) & 15, r3 = (e3 >> 16) & 15;
            int r4 = (e4 >> 16) & 15, r5 = (e5 >> 16) & 15;
            int r6 = (e6 >> 16) & 15, r7 = (e7 >> 16) & 15;
            atomicAdd(&acc[r0][2 * lane], bfl(v0)); atomicAdd(&acc[r0][2 * lane + 1], bfh(v0));
            atomicAdd(&acc[r1][2 * lane], bfl(v1)); atomicAdd(&acc[r1][2 * lane + 1], bfh(v1));
            atomicAdd(&acc[r2][2 * lane], bfl(v2)); atomicAdd(&acc[r2][2 * lane + 1], bfh(v2));
            atomicAdd(&acc[r3][2 * lane], bfl(v3)); atomicAdd(&acc[r3][2 * lane + 1], bfh(v3));
            atomicAdd(&acc[r4][2 * lane], bfl(v4)); atomicAdd(&acc[r4][2 * lane + 1], bfh(v4));
            atomicAdd(&acc[r5][2 * lane], bfl(v5)); atomicAdd(&acc[r5][2 * lane + 1], bfh(v5));
            atomicAdd(&acc[r6][2 * lane], bfl(v6)); atomicAdd(&acc[r6][2 * lane + 1], bfh(v6));
            atomicAdd(&acc[r7][2 * lane], bfl(v7)); atomicAdd(&acc[r7][2 * lane + 1], bfh(v7));
        }
        for (; t < m; ++t) {
            uint32 ev = __builtin_amdgcn_readlane(v_l, t);
            uint32 v = xb[((ev & 0xffffu) << 6) + lane];
            int r = (ev >> 16) & 15;
            atomicAdd(&acc[r][2 * lane], bfl(v));
            atomicAdd(&acc[r][2 * lane + 1], bfh(v));
        }
    }
    __syncthreads();

    // ---- matvec phase: wave wv owns rows [wv*NPW, wv*NPW+NPW) ----
    const int f0 = lane, f1 = lane + 64;
    const int rbase = wv * NPW;

    float acc0[NPW], acc1[NPW];
    #pragma unroll
    for (int i = 0; i < NPW; ++i) { acc0[i] = 0.f; acc1[i] = 0.f; }

    for (int k2 = 0; k2 < 64; k2 += 2) {
        uint32 wm00 = WTmb[k2 * D + f0];
        uint32 wm01 = WTmb[(k2 + 1) * D + f0];
        uint32 wm10 = WTmb[k2 * D + f1];
        uint32 wm11 = WTmb[(k2 + 1) * D + f1];
        float w00l = bfl(wm00), w00h = bfh(wm00), w01l = bfl(wm01), w01h = bfh(wm01);
        float w10l = bfl(wm10), w10h = bfh(wm10), w11l = bfl(wm11), w11h = bfh(wm11);
        #pragma unroll
        for (int i = 0; i < NPW; ++i) {
            float4 a4 = *(const float4*)&acc[rbase + i][2 * k2];
            acc0[i] += a4.x * w00l + a4.y * w00h + a4.z * w01l + a4.w * w01h;
            acc1[i] += a4.x * w10l + a4.y * w10h + a4.z * w11l + a4.w * w11h;
        }
    }

    float bm0 = bm[f0], bm1 = bm[f1];
    #pragma unroll
    for (int i = 0; i < NPW; ++i) {
        float cnt = (float)degl[rbase + i];
        float inv = 1.0f / (cnt + EPS);
        o_lds[rbase + i][f0] = (acc0[i] + cnt * bm0) * inv;
        o_lds[rbase + i][f1] = (acc1[i] + cnt * bm1) * inv;
    }
    __syncthreads();

    #pragma unroll
    for (int i = 0; i < NPW; ++i) { acc0[i] = 0.f; acc1[i] = 0.f; }

    for (int k2 = 0; k2 < 64; k2 += 2) {
        uint32 wu00 = WTub[k2 * D + f0];
        uint32 wu01 = WTub[(k2 + 1) * D + f0];
        uint32 wu10 = WTub[k2 * D + f1];
        uint32 wu11 = WTub[(k2 + 1) * D + f1];
        float w00l = bfl(wu00), w00h = bfh(wu00), w01l = bfl(wu01), w01h = bfh(wu01);
        float w10l = bfl(wu10), w10h = bfh(wu10), w11l = bfl(wu11), w11h = bfh(wu11);
        #pragma unroll
        for (int i = 0; i < NPW; ++i) {
            float4 a4 = *(const float4*)&o_lds[rbase + i][2 * k2];
            acc0[i] += a4.x * w00l + a4.y * w00h + a4.z * w01l + a4.w * w01h;
            acc1[i] += a4.x * w10l + a4.y * w10h + a4.z * w11l + a4.w * w11h;
        }
    }

    float bu0 = bu[f0], bu1 = bu[f1];
    #pragma unroll
    for (int i = 0; i < NPW; ++i) {
        int n = blockIdx.x * RPB + rbase + i;
        if (n >= N_) continue;
        float t0 = acc0[i] + bu0;
        float t1 = acc1[i] + bu1;
        float v = t0 * t0 + t1 * t1;
        #pragma unroll
        for (int o = 32; o > 0; o >>= 1) v += __shfl_xor(v, o);
        float scale = 1.0f / (sqrtf(v) + EPS);
        out[n * D + f0] = t0 * scale;
        out[n * D + f1] = t1 * scale;
    }
}

// ---------------- launch ----------------

extern "C" void kernel_launch(void* const* d_in, const int* in_sizes, int n_in,
                              void* d_out, int out_size, void* d_ws, size_t ws_size,
                              hipStream_t stream) {
    const float* x  = (const float*)d_in[0];
    const int*   ei = (const int*)d_in[1];
    const float* Wm = (const float*)d_in[2];
    const float* bm = (const float*)d_in[3];
    const float* Wu = (const float*)d_in[4];
    const float* bu = (const float*)d_in[5];
    float* out = (float*)d_out;

    const int N_ = in_sizes[0] / D;        // 10000
    const int E_ = in_sizes[1] / 2;        // 640000
    const int NX = N_ * (D / 2);           // packed x pairs
    const int NB = (N_ + RPB - 1) / RPB;   // 625 buckets

    int* bhist   = (int*)d_ws;                    // NB
    int* bcur    = bhist + NB;                    // NB
    int* bstart  = bcur + NB;                     // NB+1
    uint32* xb   = (uint32*)(bstart + NB + 1);    // N*64
    uint32* eb   = xb + NX;                       // E packed edges
    uint32* WTmb = eb + E_;                       // 64*128
    uint32* WTub = WTmb + 64 * D;                 // 64*128

    hipMemsetAsync(bhist, 0, 2 * (size_t)NB * sizeof(int), stream);

    k_prep<<<(NX + 255) / 256, 256, 0, stream>>>(x, xb, NX);
    k_wprep<<<(64 * D + 255) / 256, 256, 0, stream>>>(Wm, Wu, WTmb, WTub);

    int nplace = (E_ + EPB - 1) / EPB;   // 79
    k_bhist<<<nplace, 256, 0, stream>>>(ei, bhist, E_, NB);
    k_scan<<<1, 1024, 0, stream>>>(bhist, bstart, NB);
    k_bplace<<<nplace, 256, 0, stream>>>(ei, bstart, bcur, eb, E_, NB);

    k_fused<<<NB, 256, 0, stream>>>(xb, bstart, eb, WTmb, bm, WTub, bu, out, N_);
}

// Round 5
// 582.472 us; speedup vs baseline: 1.0006x; 1.0006x over previous
//
#include <hip/hip_runtime.h>
#include <hip/hip_bf16.h>

#define D 128            // D_IN == D_OUT == 128
#define RPB 16           // rows per bucket
#define NBMAX 640        // max buckets (N<=10240)
#define EPB 8192         // edges per block in hist/place
#define NPW 4            // rows per wave in matvec phase
#define EPS 1e-8f

typedef unsigned int uint32;

__device__ __forceinline__ uint32 f2bf_rne(float f) {
    uint32 u = __float_as_uint(f);
    return (u + 0x7fffu + ((u >> 16) & 1u)) >> 16;   // round-nearest-even
}
__device__ __forceinline__ float bfl(uint32 u) { return __uint_as_float(u << 16); }
__device__ __forceinline__ float bfh(uint32 u) { return __uint_as_float(u & 0xffff0000u); }

// ---------------- prep: bf16-pack x ----------------

__global__ void k_prep(const float* __restrict__ x, uint32* __restrict__ xb, int NX) {
    int i = blockIdx.x * blockDim.x + threadIdx.x;
    if (i < NX) {
        float2 f = ((const float2*)x)[i];
        xb[i] = f2bf_rne(f.x) | (f2bf_rne(f.y) << 16);
    }
}

// ---------------- W transpose + bf16 pack ----------------

__global__ void k_wprep(const float* __restrict__ Wm, const float* __restrict__ Wu,
                        uint32* __restrict__ WTmb, uint32* __restrict__ WTub) {
    int i = blockIdx.x * blockDim.x + threadIdx.x;   // 64*128 threads
    if (i >= 64 * 128) return;
    int k2 = i >> 7, f = i & 127;
    WTmb[i] = f2bf_rne(Wm[f * D + 2 * k2]) | (f2bf_rne(Wm[f * D + 2 * k2 + 1]) << 16);
    WTub[i] = f2bf_rne(Wu[f * D + 2 * k2]) | (f2bf_rne(Wu[f * D + 2 * k2 + 1]) << 16);
}

// ---------------- bucket histogram (LDS pre-aggregated) ----------------

__global__ __launch_bounds__(256) void k_bhist(const int* __restrict__ ei,
                                               int* __restrict__ bhist, int E_, int NB) {
    __shared__ int h[NBMAX];
    for (int i = threadIdx.x; i < NB; i += 256) h[i] = 0;
    __syncthreads();
    int base = blockIdx.x * EPB;
    int hi = min(base + EPB, E_);
    for (int i = base + threadIdx.x; i < hi; i += 256)
        atomicAdd(&h[ei[i] >> 4], 1);
    __syncthreads();
    for (int i = threadIdx.x; i < NB; i += 256)
        if (h[i]) atomicAdd(&bhist[i], h[i]);
}

// ---------------- scan (generic exclusive scan -> starts) ----------------

__global__ void k_scan(const int* __restrict__ deg, int* __restrict__ starts, int N_) {
    __shared__ int part[1024];
    int t = threadIdx.x;
    int chunk = (N_ + 1023) / 1024;
    int s = t * chunk;
    int e = min(N_, s + chunk);
    int sum = 0;
    for (int i = s; i < e; ++i) sum += deg[i];
    part[t] = sum;
    __syncthreads();
    for (int off = 1; off < 1024; off <<= 1) {
        int u = (t >= off) ? part[t - off] : 0;
        __syncthreads();
        part[t] += u;
        __syncthreads();
    }
    int run = part[t] - sum;
    for (int i = s; i < e; ++i) { starts[i] = run; run += deg[i]; }
    if (t == 1023) starts[N_] = part[1023];
}

// ---------------- place: block-local counting sort by bucket, coalesced out ----

__global__ __launch_bounds__(256) void k_bplace(
        const int* __restrict__ ei, const int* __restrict__ bstart,
        int* __restrict__ bcur, uint32* __restrict__ eb, int E_, int NB) {
    __shared__ int h[NBMAX];      // local hist (counts)
    __shared__ int off[NBMAX];    // local exclusive start -> running cursor
    __shared__ int bias[NBMAX];   // global_base - local_start
    __shared__ uint32 stg[EPB];   // sorted staging (32 KB)

    const int tid = threadIdx.x;
    const int base = blockIdx.x * EPB;
    const int nE = min(EPB, E_ - base);

    for (int i = tid; i < NB; i += 256) h[i] = 0;
    __syncthreads();

    // pass 1: local histogram
    for (int i = tid; i < nE; i += 256)
        atomicAdd(&h[ei[base + i] >> 4], 1);
    __syncthreads();

    // exclusive scan of h -> off, by one wave (lane handles 10 bins)
    if (tid < 64) {
        int b0 = tid * 10;
        int loc[10];
        int lsum = 0;
        #pragma unroll
        for (int j = 0; j < 10; ++j) {
            int b = b0 + j;
            int v = (b < NB) ? h[b] : 0;
            loc[j] = lsum;
            lsum += v;
        }
        int run = lsum;
        #pragma unroll
        for (int o = 1; o < 64; o <<= 1) {
            int u = __shfl_up(run, o);
            if (tid >= o) run += u;
        }
        int excl = run - lsum;
        #pragma unroll
        for (int j = 0; j < 10; ++j) {
            int b = b0 + j;
            if (b < NB) off[b] = excl + loc[j];
        }
    }
    __syncthreads();

    // reserve global ranges per bucket
    for (int b = tid; b < NB; b += 256) {
        int c = h[b];
        if (c) {
            int g = atomicAdd(&bcur[b], c);
            bias[b] = (bstart[b] + g) - off[b];
        }
    }
    __syncthreads();

    // pass 2: scatter into sorted staging
    for (int i = tid; i < nE; i += 256) {
        int r = ei[base + i];
        int c = ei[E_ + base + i];
        int b = r >> 4;
        int p = atomicAdd(&off[b], 1);
        stg[p] = ((uint32)r << 16) | (uint32)c;
    }
    __syncthreads();

    // pass 3: linear write-out (coalesced runs per bucket)
    for (int i = tid; i < nE; i += 256) {
        uint32 v = stg[i];
        int b = v >> 20;               // (r>>16... r = v>>16, bucket = r>>4
        eb[bias[b] + i] = v;
    }
}

// ---------------- fused: bucket gather + 2x matvec + mean + norm ----------------
// one block per bucket (16 rows); 256 threads = 4 waves

__global__ __launch_bounds__(256) void k_fused(
        const uint32* __restrict__ xb, const int* __restrict__ bstart,
        const uint32* __restrict__ eb,
        const uint32* __restrict__ WTmb, const float* __restrict__ bm,
        const uint32* __restrict__ WTub, const float* __restrict__ bu,
        float* __restrict__ out, int N_) {
    __shared__ float acc[RPB][D];    // 8 KB aggregated sums
    __shared__ float o_lds[RPB][D];  // 8 KB intermediate
    __shared__ int degl[RPB];

    const int tid  = threadIdx.x;
    const int lane = tid & 63;
    const int wv   = tid >> 6;

    for (int i = tid; i < RPB * D; i += 256) ((float*)acc)[i] = 0.f;
    if (tid < RPB) degl[tid] = 0;
    __syncthreads();

    const int s = bstart[blockIdx.x];
    const int e = bstart[blockIdx.x + 1];

    // ---- gather: each wave takes 64-edge chunks, strided by 256 ----
    for (int ii = s + wv * 64; ii < e; ii += 256) {
        int m = min(64, e - ii);
        uint32 v_l = (lane < m) ? eb[ii + lane] : 0;
        if (lane < m) atomicAdd(&degl[(v_l >> 16) & 15], 1);
        int t = 0;
        for (; t + 8 <= m; t += 8) {
            uint32 e0 = __builtin_amdgcn_readlane(v_l, t + 0);
            uint32 e1 = __builtin_amdgcn_readlane(v_l, t + 1);
            uint32 e2 = __builtin_amdgcn_readlane(v_l, t + 2);
            uint32 e3 = __builtin_amdgcn_readlane(v_l, t + 3);
            uint32 e4 = __builtin_amdgcn_readlane(v_l, t + 4);
            uint32 e5 = __builtin_amdgcn_readlane(v_l, t + 5);
            uint32 e6 = __builtin_amdgcn_readlane(v_l, t + 6);
            uint32 e7 = __builtin_amdgcn_readlane(v_l, t + 7);
            uint32 v0 = xb[((e0 & 0xffffu) << 6) + lane];
            uint32 v1 = xb[((e1 & 0xffffu) << 6) + lane];
            uint32 v2 = xb[((e2 & 0xffffu) << 6) + lane];
            uint32 v3 = xb[((e3 & 0xffffu) << 6) + lane];
            uint32 v4 = xb[((e4 & 0xffffu) << 6) + lane];
            uint32 v5 = xb[((e5 & 0xffffu) << 6) + lane];
            uint32 v6 = xb[((e6 & 0xffffu) << 6) + lane];
            uint32 v7 = xb[((e7 & 0xffffu) << 6) + lane];
            int r0 = (e0 >> 16) & 15, r1 = (e1 >> 16) & 15;
            int r2 = (e2 >> 16) & 15, r3 = (e3 >> 16) & 15;
            int r4 = (e4 >> 16) & 15, r5 = (e5 >> 16) & 15;
            int r6 = (e6 >> 16) & 15, r7 = (e7 >> 16) & 15;
            atomicAdd(&acc[r0][2 * lane], bfl(v0)); atomicAdd(&acc[r0][2 * lane + 1], bfh(v0));
            atomicAdd(&acc[r1][2 * lane], bfl(v1)); atomicAdd(&acc[r1][2 * lane + 1], bfh(v1));
            atomicAdd(&acc[r2][2 * lane], bfl(v2)); atomicAdd(&acc[r2][2 * lane + 1], bfh(v2));
            atomicAdd(&acc[r3][2 * lane], bfl(v3)); atomicAdd(&acc[r3][2 * lane + 1], bfh(v3));
            atomicAdd(&acc[r4][2 * lane], bfl(v4)); atomicAdd(&acc[r4][2 * lane + 1], bfh(v4));
            atomicAdd(&acc[r5][2 * lane], bfl(v5)); atomicAdd(&acc[r5][2 * lane + 1], bfh(v5));
            atomicAdd(&acc[r6][2 * lane], bfl(v6)); atomicAdd(&acc[r6][2 * lane + 1], bfh(v6));
            atomicAdd(&acc[r7][2 * lane], bfl(v7)); atomicAdd(&acc[r7][2 * lane + 1], bfh(v7));
        }
        for (; t < m; ++t) {
            uint32 ev = __builtin_amdgcn_readlane(v_l, t);
            uint32 v = xb[((ev & 0xffffu) << 6) + lane];
            int r = (ev >> 16) & 15;
            atomicAdd(&acc[r][2 * lane], bfl(v));
            atomicAdd(&acc[r][2 * lane + 1], bfh(v));
        }
    }
    __syncthreads();

    // ---- matvec phase: wave wv owns rows [wv*NPW, wv*NPW+NPW) ----
    const int f0 = lane, f1 = lane + 64;
    const int rbase = wv * NPW;

    float acc0[NPW], acc1[NPW];
    #pragma unroll
    for (int i = 0; i < NPW; ++i) { acc0[i] = 0.f; acc1[i] = 0.f; }

    for (int k2 = 0; k2 < 64; k2 += 2) {
        uint32 wm00 = WTmb[k2 * D + f0];
        uint32 wm01 = WTmb[(k2 + 1) * D + f0];
        uint32 wm10 = WTmb[k2 * D + f1];
        uint32 wm11 = WTmb[(k2 + 1) * D + f1];
        float w00l = bfl(wm00), w00h = bfh(wm00), w01l = bfl(wm01), w01h = bfh(wm01);
        float w10l = bfl(wm10), w10h = bfh(wm10), w11l = bfl(wm11), w11h = bfh(wm11);
        #pragma unroll
        for (int i = 0; i < NPW; ++i) {
            float4 a4 = *(const float4*)&acc[rbase + i][2 * k2];
            acc0[i] += a4.x * w00l + a4.y * w00h + a4.z * w01l + a4.w * w01h;
            acc1[i] += a4.x * w10l + a4.y * w10h + a4.z * w11l + a4.w * w11h;
        }
    }

    float bm0 = bm[f0], bm1 = bm[f1];
    #pragma unroll
    for (int i = 0; i < NPW; ++i) {
        float cnt = (float)degl[rbase + i];
        float inv = 1.0f / (cnt + EPS);
        o_lds[rbase + i][f0] = (acc0[i] + cnt * bm0) * inv;
        o_lds[rbase + i][f1] = (acc1[i] + cnt * bm1) * inv;
    }
    __syncthreads();

    #pragma unroll
    for (int i = 0; i < NPW; ++i) { acc0[i] = 0.f; acc1[i] = 0.f; }

    for (int k2 = 0; k2 < 64; k2 += 2) {
        uint32 wu00 = WTub[k2 * D + f0];
        uint32 wu01 = WTub[(k2 + 1) * D + f0];
        uint32 wu10 = WTub[k2 * D + f1];
        uint32 wu11 = WTub[(k2 + 1) * D + f1];
        float w00l = bfl(wu00), w00h = bfh(wu00), w01l = bfl(wu01), w01h = bfh(wu01);
        float w10l = bfl(wu10), w10h = bfh(wu10), w11l = bfl(wu11), w11h = bfh(wu11);
        #pragma unroll
        for (int i = 0; i < NPW; ++i) {
            float4 a4 = *(const float4*)&o_lds[rbase + i][2 * k2];
            acc0[i] += a4.x * w00l + a4.y * w00h + a4.z * w01l + a4.w * w01h;
            acc1[i] += a4.x * w10l + a4.y * w10h + a4.z * w11l + a4.w * w11h;
        }
    }

    float bu0 = bu[f0], bu1 = bu[f1];
    #pragma unroll
    for (int i = 0; i < NPW; ++i) {
        int n = blockIdx.x * RPB + rbase + i;
        if (n >= N_) continue;
        float t0 = acc0[i] + bu0;
        float t1 = acc1[i] + bu1;
        float v = t0 * t0 + t1 * t1;
        #pragma unroll
        for (int o = 32; o > 0; o >>= 1) v += __shfl_xor(v, o);
        float scale = 1.0f / (sqrtf(v) + EPS);
        out[n * D + f0] = t0 * scale;
        out[n * D + f1] = t1 * scale;
    }
}

// ---------------- launch ----------------

extern "C" void kernel_launch(void* const* d_in, const int* in_sizes, int n_in,
                              void* d_out, int out_size, void* d_ws, size_t ws_size,
                              hipStream_t stream) {
    const float* x  = (const float*)d_in[0];
    const int*   ei = (const int*)d_in[1];
    const float* Wm = (const float*)d_in[2];
    const float* bm = (const float*)d_in[3];
    const float* Wu = (const float*)d_in[4];
    const float* bu = (const float*)d_in[5];
    float* out = (float*)d_out;

    const int N_ = in_sizes[0] / D;        // 10000
    const int E_ = in_sizes[1] / 2;        // 640000
    const int NX = N_ * (D / 2);           // packed x pairs
    const int NB = (N_ + RPB - 1) / RPB;   // 625 buckets

    int* bhist   = (int*)d_ws;                    // NB
    int* bcur    = bhist + NB;                    // NB
    int* bstart  = bcur + NB;                     // NB+1
    uint32* xb   = (uint32*)(bstart + NB + 1);    // N*64
    uint32* eb   = xb + NX;                       // E packed edges
    uint32* WTmb = eb + E_;                       // 64*128
    uint32* WTub = WTmb + 64 * D;                 // 64*128

    hipMemsetAsync(bhist, 0, 2 * (size_t)NB * sizeof(int), stream);

    k_prep<<<(NX + 255) / 256, 256, 0, stream>>>(x, xb, NX);
    k_wprep<<<(64 * D + 255) / 256, 256, 0, stream>>>(Wm, Wu, WTmb, WTub);

    int nplace = (E_ + EPB - 1) / EPB;   // 79
    k_bhist<<<nplace, 256, 0, stream>>>(ei, bhist, E_, NB);
    k_scan<<<1, 1024, 0, stream>>>(bhist, bstart, NB);
    k_bplace<<<nplace, 256, 0, stream>>>(ei, bstart, bcur, eb, E_, NB);

    k_fused<<<NB, 256, 0, stream>>>(xb, bstart, eb, WTmb, bm, WTub, bu, out, N_);
}

// Round 6
// 582.373 us; speedup vs baseline: 1.0008x; 1.0002x over previous
//
#include <hip/hip_runtime.h>
#include <hip/hip_bf16.h>

#define D 128            // D_IN == D_OUT == 128
#define RPB 16           // rows per bucket
#define NBMAX 640        // max buckets (N<=10240)
#define EPB 8192         // edges per block in hist/place
#define NPW 4            // rows per wave in matvec phase
#define EPS 1e-8f

typedef unsigned int uint32;

__device__ __forceinline__ uint32 f2bf_rne(float f) {
    uint32 u = __float_as_uint(f);
    return (u + 0x7fffu + ((u >> 16) & 1u)) >> 16;   // round-nearest-even
}
__device__ __forceinline__ float bfl(uint32 u) { return __uint_as_float(u << 16); }
__device__ __forceinline__ float bfh(uint32 u) { return __uint_as_float(u & 0xffff0000u); }

// ---------------- prep: bf16-pack x ----------------

__global__ void k_prep(const float* __restrict__ x, uint32* __restrict__ xb, int NX) {
    int i = blockIdx.x * blockDim.x + threadIdx.x;
    if (i < NX) {
        float2 f = ((const float2*)x)[i];
        xb[i] = f2bf_rne(f.x) | (f2bf_rne(f.y) << 16);
    }
}

// ---------------- W transpose + bf16 pack ----------------

__global__ void k_wprep(const float* __restrict__ Wm, const float* __restrict__ Wu,
                        uint32* __restrict__ WTmb, uint32* __restrict__ WTub) {
    int i = blockIdx.x * blockDim.x + threadIdx.x;   // 64*128 threads
    if (i >= 64 * 128) return;
    int k2 = i >> 7, f = i & 127;
    WTmb[i] = f2bf_rne(Wm[f * D + 2 * k2]) | (f2bf_rne(Wm[f * D + 2 * k2 + 1]) << 16);
    WTub[i] = f2bf_rne(Wu[f * D + 2 * k2]) | (f2bf_rne(Wu[f * D + 2 * k2 + 1]) << 16);
}

// ---------------- bucket histogram (LDS pre-aggregated) ----------------

__global__ __launch_bounds__(256) void k_bhist(const int* __restrict__ ei,
                                               int* __restrict__ bhist, int E_, int NB) {
    __shared__ int h[NBMAX];
    for (int i = threadIdx.x; i < NB; i += 256) h[i] = 0;
    __syncthreads();
    int base = blockIdx.x * EPB;
    int hi = min(base + EPB, E_);
    for (int i = base + threadIdx.x; i < hi; i += 256)
        atomicAdd(&h[ei[i] >> 4], 1);
    __syncthreads();
    for (int i = threadIdx.x; i < NB; i += 256)
        if (h[i]) atomicAdd(&bhist[i], h[i]);
}

// ---------------- scan (generic exclusive scan -> starts) ----------------

__global__ void k_scan(const int* __restrict__ deg, int* __restrict__ starts, int N_) {
    __shared__ int part[1024];
    int t = threadIdx.x;
    int chunk = (N_ + 1023) / 1024;
    int s = t * chunk;
    int e = min(N_, s + chunk);
    int sum = 0;
    for (int i = s; i < e; ++i) sum += deg[i];
    part[t] = sum;
    __syncthreads();
    for (int off = 1; off < 1024; off <<= 1) {
        int u = (t >= off) ? part[t - off] : 0;
        __syncthreads();
        part[t] += u;
        __syncthreads();
    }
    int run = part[t] - sum;
    for (int i = s; i < e; ++i) { starts[i] = run; run += deg[i]; }
    if (t == 1023) starts[N_] = part[1023];
}

// ---------------- place: block-local counting sort by bucket, coalesced out ----

__global__ __launch_bounds__(256) void k_bplace(
        const int* __restrict__ ei, const int* __restrict__ bstart,
        int* __restrict__ bcur, uint32* __restrict__ eb, int E_, int NB) {
    __shared__ int h[NBMAX];      // local hist (counts)
    __shared__ int off[NBMAX];    // local exclusive start -> running cursor
    __shared__ int bias[NBMAX];   // global_base - local_start
    __shared__ uint32 stg[EPB];   // sorted staging (32 KB)

    const int tid = threadIdx.x;
    const int base = blockIdx.x * EPB;
    const int nE = min(EPB, E_ - base);

    for (int i = tid; i < NB; i += 256) h[i] = 0;
    __syncthreads();

    // pass 1: local histogram
    for (int i = tid; i < nE; i += 256)
        atomicAdd(&h[ei[base + i] >> 4], 1);
    __syncthreads();

    // exclusive scan of h -> off, by one wave (lane handles 10 bins)
    if (tid < 64) {
        int b0 = tid * 10;
        int loc[10];
        int lsum = 0;
        #pragma unroll
        for (int j = 0; j < 10; ++j) {
            int b = b0 + j;
            int v = (b < NB) ? h[b] : 0;
            loc[j] = lsum;
            lsum += v;
        }
        int run = lsum;
        #pragma unroll
        for (int o = 1; o < 64; o <<= 1) {
            int u = __shfl_up(run, o);
            if (tid >= o) run += u;
        }
        int excl = run - lsum;
        #pragma unroll
        for (int j = 0; j < 10; ++j) {
            int b = b0 + j;
            if (b < NB) off[b] = excl + loc[j];
        }
    }
    __syncthreads();

    // reserve global ranges per bucket
    for (int b = tid; b < NB; b += 256) {
        int c = h[b];
        if (c) {
            int g = atomicAdd(&bcur[b], c);
            bias[b] = (bstart[b] + g) - off[b];
        }
    }
    __syncthreads();

    // pass 2: scatter into sorted staging
    for (int i = tid; i < nE; i += 256) {
        int r = ei[base + i];
        int c = ei[E_ + base + i];
        int b = r >> 4;
        int p = atomicAdd(&off[b], 1);
        stg[p] = ((uint32)r << 16) | (uint32)c;
    }
    __syncthreads();

    // pass 3: linear write-out (coalesced runs per bucket)
    for (int i = tid; i < nE; i += 256) {
        uint32 v = stg[i];
        int b = v >> 20;               // (r>>16... r = v>>16, bucket = r>>4
        eb[bias[b] + i] = v;
    }
}

// ---------------- fused: bucket gather + 2x matvec + mean + norm ----------------
// one block per bucket (16 rows); 256 threads = 4 waves

__global__ __launch_bounds__(256) void k_fused(
        const uint32* __restrict__ xb, const int* __restrict__ bstart,
        const uint32* __restrict__ eb,
        const uint32* __restrict__ WTmb, const float* __restrict__ bm,
        const uint32* __restrict__ WTub, const float* __restrict__ bu,
        float* __restrict__ out, int N_) {
    __shared__ float acc[RPB][D];    // 8 KB aggregated sums
    __shared__ float o_lds[RPB][D];  // 8 KB intermediate
    __shared__ int degl[RPB];

    const int tid  = threadIdx.x;
    const int lane = tid & 63;
    const int wv   = tid >> 6;

    for (int i = tid; i < RPB * D; i += 256) ((float*)acc)[i] = 0.f;
    if (tid < RPB) degl[tid] = 0;
    __syncthreads();

    const int s = bstart[blockIdx.x];
    const int e = bstart[blockIdx.x + 1];

    // ---- gather: each wave takes 64-edge chunks, strided by 256 ----
    for (int ii = s + wv * 64; ii < e; ii += 256) {
        int m = min(64, e - ii);
        uint32 v_l = (lane < m) ? eb[ii + lane] : 0;
        if (lane < m) atomicAdd(&degl[(v_l >> 16) & 15], 1);
        int t = 0;
        for (; t + 8 <= m; t += 8) {
            uint32 e0 = __builtin_amdgcn_readlane(v_l, t + 0);
            uint32 e1 = __builtin_amdgcn_readlane(v_l, t + 1);
            uint32 e2 = __builtin_amdgcn_readlane(v_l, t + 2);
            uint32 e3 = __builtin_amdgcn_readlane(v_l, t + 3);
            uint32 e4 = __builtin_amdgcn_readlane(v_l, t + 4);
            uint32 e5 = __builtin_amdgcn_readlane(v_l, t + 5);
            uint32 e6 = __builtin_amdgcn_readlane(v_l, t + 6);
            uint32 e7 = __builtin_amdgcn_readlane(v_l, t + 7);
            uint32 v0 = xb[((e0 & 0xffffu) << 6) + lane];
            uint32 v1 = xb[((e1 & 0xffffu) << 6) + lane];
            uint32 v2 = xb[((e2 & 0xffffu) << 6) + lane];
            uint32 v3 = xb[((e3 & 0xffffu) << 6) + lane];
            uint32 v4 = xb[((e4 & 0xffffu) << 6) + lane];
            uint32 v5 = xb[((e5 & 0xffffu) << 6) + lane];
            uint32 v6 = xb[((e6 & 0xffffu) << 6) + lane];
            uint32 v7 = xb[((e7 & 0xffffu) << 6) + lane];
            int r0 = (e0 >> 16) & 15, r1 = (e1 >> 16) & 15;
            int r2 = (e2 >> 16) & 15, r3 = (e3 >> 16) & 15;
            int r4 = (e4 >> 16) & 15, r5 = (e5 >> 16) & 15;
            int r6 = (e6 >> 16) & 15, r7 = (e7 >> 16) & 15;
            atomicAdd(&acc[r0][2 * lane], bfl(v0)); atomicAdd(&acc[r0][2 * lane + 1], bfh(v0));
            atomicAdd(&acc[r1][2 * lane], bfl(v1)); atomicAdd(&acc[r1][2 * lane + 1], bfh(v1));
            atomicAdd(&acc[r2][2 * lane], bfl(v2)); atomicAdd(&acc[r2][2 * lane + 1], bfh(v2));
            atomicAdd(&acc[r3][2 * lane], bfl(v3)); atomicAdd(&acc[r3][2 * lane + 1], bfh(v3));
            atomicAdd(&acc[r4][2 * lane], bfl(v4)); atomicAdd(&acc[r4][2 * lane + 1], bfh(v4));
            atomicAdd(&acc[r5][2 * lane], bfl(v5)); atomicAdd(&acc[r5][2 * lane + 1], bfh(v5));
            atomicAdd(&acc[r6][2 * lane], bfl(v6)); atomicAdd(&acc[r6][2 * lane + 1], bfh(v6));
            atomicAdd(&acc[r7][2 * lane], bfl(v7)); atomicAdd(&acc[r7][2 * lane + 1], bfh(v7));
        }
        for (; t < m; ++t) {
            uint32 ev = __builtin_amdgcn_readlane(v_l, t);
            uint32 v = xb[((ev & 0xffffu) << 6) + lane];
            int r = (ev >> 16) & 15;
            atomicAdd(&acc[r][2 * lane], bfl(v));
            atomicAdd(&acc[r][2 * lane + 1], bfh(v));
        }
    }
    __syncthreads();

    // ---- matvec phase: wave wv owns rows [wv*NPW, wv*NPW+NPW) ----
    const int f0 = lane, f1 = lane + 64;
    const int rbase = wv * NPW;

    float acc0[NPW], acc1[NPW];
    #pragma unroll
    for (int i = 0; i < NPW; ++i) { acc0[i] = 0.f; acc1[i] = 0.f; }

    for (int k2 = 0; k2 < 64; k2 += 2) {
        uint32 wm00 = WTmb[k2 * D + f0];
        uint32 wm01 = WTmb[(k2 + 1) * D + f0];
        uint32 wm10 = WTmb[k2 * D + f1];
        uint32 wm11 = WTmb[(k2 + 1) * D + f1];
        float w00l = bfl(wm00), w00h = bfh(wm00), w01l = bfl(wm01), w01h = bfh(wm01);
        float w10l = bfl(wm10), w10h = bfh(wm10), w11l = bfl(wm11), w11h = bfh(wm11);
        #pragma unroll
        for (int i = 0; i < NPW; ++i) {
            float4 a4 = *(const float4*)&acc[rbase + i][2 * k2];
            acc0[i] += a4.x * w00l + a4.y * w00h + a4.z * w01l + a4.w * w01h;
            acc1[i] += a4.x * w10l + a4.y * w10h + a4.z * w11l + a4.w * w11h;
        }
    }

    float bm0 = bm[f0], bm1 = bm[f1];
    #pragma unroll
    for (int i = 0; i < NPW; ++i) {
        float cnt = (float)degl[rbase + i];
        float inv = 1.0f / (cnt + EPS);
        o_lds[rbase + i][f0] = (acc0[i] + cnt * bm0) * inv;
        o_lds[rbase + i][f1] = (acc1[i] + cnt * bm1) * inv;
    }
    __syncthreads();

    #pragma unroll
    for (int i = 0; i < NPW; ++i) { acc0[i] = 0.f; acc1[i] = 0.f; }

    for (int k2 = 0; k2 < 64; k2 += 2) {
        uint32 wu00 = WTub[k2 * D + f0];
        uint32 wu01 = WTub[(k2 + 1) * D + f0];
        uint32 wu10 = WTub[k2 * D + f1];
        uint32 wu11 = WTub[(k2 + 1) * D + f1];
        float w00l = bfl(wu00), w00h = bfh(wu00), w01l = bfl(wu01), w01h = bfh(wu01);
        float w10l = bfl(wu10), w10h = bfh(wu10), w11l = bfl(wu11), w11h = bfh(wu11);
        #pragma unroll
        for (int i = 0; i < NPW; ++i) {
            float4 a4 = *(const float4*)&o_lds[rbase + i][2 * k2];
            acc0[i] += a4.x * w00l + a4.y * w00h + a4.z * w01l + a4.w * w01h;
            acc1[i] += a4.x * w10l + a4.y * w10h + a4.z * w11l + a4.w * w11h;
        }
    }

    float bu0 = bu[f0], bu1 = bu[f1];
    #pragma unroll
    for (int i = 0; i < NPW; ++i) {
        int n = blockIdx.x * RPB + rbase + i;
        if (n >= N_) continue;
        float t0 = acc0[i] + bu0;
        float t1 = acc1[i] + bu1;
        float v = t0 * t0 + t1 * t1;
        #pragma unroll
        for (int o = 32; o > 0; o >>= 1) v += __shfl_xor(v, o);
        float scale = 1.0f / (sqrtf(v) + EPS);
        out[n * D + f0] = t0 * scale;
        out[n * D + f1] = t1 * scale;
    }
}

// ---------------- launch ----------------

extern "C" void kernel_launch(void* const* d_in, const int* in_sizes, int n_in,
                              void* d_out, int out_size, void* d_ws, size_t ws_size,
                              hipStream_t stream) {
    const float* x  = (const float*)d_in[0];
    const int*   ei = (const int*)d_in[1];
    const float* Wm = (const float*)d_in[2];
    const float* bm = (const float*)d_in[3];
    const float* Wu = (const float*)d_in[4];
    const float* bu = (const float*)d_in[5];
    float* out = (float*)d_out;

    const int N_ = in_sizes[0] / D;        // 10000
    const int E_ = in_sizes[1] / 2;        // 640000
    const int NX = N_ * (D / 2);           // packed x pairs
    const int NB = (N_ + RPB - 1) / RPB;   // 625 buckets

    int* bhist   = (int*)d_ws;                    // NB
    int* bcur    = bhist + NB;                    // NB
    int* bstart  = bcur + NB;                     // NB+1
    uint32* xb   = (uint32*)(bstart + NB + 1);    // N*64
    uint32* eb   = xb + NX;                       // E packed edges
    uint32* WTmb = eb + E_;                       // 64*128
    uint32* WTub = WTmb + 64 * D;                 // 64*128

    hipMemsetAsync(bhist, 0, 2 * (size_t)NB * sizeof(int), stream);

    k_prep<<<(NX + 255) / 256, 256, 0, stream>>>(x, xb, NX);
    k_wprep<<<(64 * D + 255) / 256, 256, 0, stream>>>(Wm, Wu, WTmb, WTub);

    int nplace = (E_ + EPB - 1) / EPB;   // 79
    k_bhist<<<nplace, 256, 0, stream>>>(ei, bhist, E_, NB);
    k_scan<<<1, 1024, 0, stream>>>(bhist, bstart, NB);
    k_bplace<<<nplace, 256, 0, stream>>>(ei, bstart, bcur, eb, E_, NB);

    k_fused<<<NB, 256, 0, stream>>>(xb, bstart, eb, WTmb, bm, WTub, bu, out, N_);
}

// Round 7
// 581.823 us; speedup vs baseline: 1.0017x; 1.0009x over previous
//
#include <hip/hip_runtime.h>
#include <hip/hip_bf16.h>

#define D 128            // D_IN == D_OUT == 128
#define RPB 16           // rows per bucket
#define NBMAX 640        // max buckets (N<=10240)
#define EPB 8192         // edges per block in hist/place
#define NPW 4            // rows per wave in matvec phase
#define EPS 1e-8f

typedef unsigned int uint32;

__device__ __forceinline__ uint32 f2bf_rne(float f) {
    uint32 u = __float_as_uint(f);
    return (u + 0x7fffu + ((u >> 16) & 1u)) >> 16;   // round-nearest-even
}
__device__ __forceinline__ float bfl(uint32 u) { return __uint_as_float(u << 16); }
__device__ __forceinline__ float bfh(uint32 u) { return __uint_as_float(u & 0xffff0000u); }

// ---------------- prep: bf16-pack x ----------------

__global__ void k_prep(const float* __restrict__ x, uint32* __restrict__ xb, int NX) {
    int i = blockIdx.x * blockDim.x + threadIdx.x;
    if (i < NX) {
        float2 f = ((const float2*)x)[i];
        xb[i] = f2bf_rne(f.x) | (f2bf_rne(f.y) << 16);
    }
}

// ---------------- W transpose + bf16 pack ----------------

__global__ void k_wprep(const float* __restrict__ Wm, const float* __restrict__ Wu,
                        uint32* __restrict__ WTmb, uint32* __restrict__ WTub) {
    int i = blockIdx.x * blockDim.x + threadIdx.x;   // 64*128 threads
    if (i >= 64 * 128) return;
    int k2 = i >> 7, f = i & 127;
    WTmb[i] = f2bf_rne(Wm[f * D + 2 * k2]) | (f2bf_rne(Wm[f * D + 2 * k2 + 1]) << 16);
    WTub[i] = f2bf_rne(Wu[f * D + 2 * k2]) | (f2bf_rne(Wu[f * D + 2 * k2 + 1]) << 16);
}

// ---------------- bucket histogram (LDS pre-aggregated) ----------------

__global__ __launch_bounds__(256) void k_bhist(const int* __restrict__ ei,
                                               int* __restrict__ bhist, int E_, int NB) {
    __shared__ int h[NBMAX];
    for (int i = threadIdx.x; i < NB; i += 256) h[i] = 0;
    __syncthreads();
    int base = blockIdx.x * EPB;
    int hi = min(base + EPB, E_);
    for (int i = base + threadIdx.x; i < hi; i += 256)
        atomicAdd(&h[ei[i] >> 4], 1);
    __syncthreads();
    for (int i = threadIdx.x; i < NB; i += 256)
        if (h[i]) atomicAdd(&bhist[i], h[i]);
}

// ---------------- scan (generic exclusive scan -> starts) ----------------

__global__ void k_scan(const int* __restrict__ deg, int* __restrict__ starts, int N_) {
    __shared__ int part[1024];
    int t = threadIdx.x;
    int chunk = (N_ + 1023) / 1024;
    int s = t * chunk;
    int e = min(N_, s + chunk);
    int sum = 0;
    for (int i = s; i < e; ++i) sum += deg[i];
    part[t] = sum;
    __syncthreads();
    for (int off = 1; off < 1024; off <<= 1) {
        int u = (t >= off) ? part[t - off] : 0;
        __syncthreads();
        part[t] += u;
        __syncthreads();
    }
    int run = part[t] - sum;
    for (int i = s; i < e; ++i) { starts[i] = run; run += deg[i]; }
    if (t == 1023) starts[N_] = part[1023];
}

// ---------------- place: block-local counting sort by bucket, coalesced out ----

__global__ __launch_bounds__(256) void k_bplace(
        const int* __restrict__ ei, const int* __restrict__ bstart,
        int* __restrict__ bcur, uint32* __restrict__ eb, int E_, int NB) {
    __shared__ int h[NBMAX];      // local hist (counts)
    __shared__ int off[NBMAX];    // local exclusive start -> running cursor
    __shared__ int bias[NBMAX];   // global_base - local_start
    __shared__ uint32 stg[EPB];   // sorted staging (32 KB)

    const int tid = threadIdx.x;
    const int base = blockIdx.x * EPB;
    const int nE = min(EPB, E_ - base);

    for (int i = tid; i < NB; i += 256) h[i] = 0;
    __syncthreads();

    // pass 1: local histogram
    for (int i = tid; i < nE; i += 256)
        atomicAdd(&h[ei[base + i] >> 4], 1);
    __syncthreads();

    // exclusive scan of h -> off, by one wave (lane handles 10 bins)
    if (tid < 64) {
        int b0 = tid * 10;
        int loc[10];
        int lsum = 0;
        #pragma unroll
        for (int j = 0; j < 10; ++j) {
            int b = b0 + j;
            int v = (b < NB) ? h[b] : 0;
            loc[j] = lsum;
            lsum += v;
        }
        int run = lsum;
        #pragma unroll
        for (int o = 1; o < 64; o <<= 1) {
            int u = __shfl_up(run, o);
            if (tid >= o) run += u;
        }
        int excl = run - lsum;
        #pragma unroll
        for (int j = 0; j < 10; ++j) {
            int b = b0 + j;
            if (b < NB) off[b] = excl + loc[j];
        }
    }
    __syncthreads();

    // reserve global ranges per bucket
    for (int b = tid; b < NB; b += 256) {
        int c = h[b];
        if (c) {
            int g = atomicAdd(&bcur[b], c);
            bias[b] = (bstart[b] + g) - off[b];
        }
    }
    __syncthreads();

    // pass 2: scatter into sorted staging
    for (int i = tid; i < nE; i += 256) {
        int r = ei[base + i];
        int c = ei[E_ + base + i];
        int b = r >> 4;
        int p = atomicAdd(&off[b], 1);
        stg[p] = ((uint32)r << 16) | (uint32)c;
    }
    __syncthreads();

    // pass 3: linear write-out (coalesced runs per bucket)
    for (int i = tid; i < nE; i += 256) {
        uint32 v = stg[i];
        int b = v >> 20;               // (r>>16... r = v>>16, bucket = r>>4
        eb[bias[b] + i] = v;
    }
}

// ---------------- fused: bucket gather + 2x matvec + mean + norm ----------------
// one block per bucket (16 rows); 256 threads = 4 waves

__global__ __launch_bounds__(256) void k_fused(
        const uint32* __restrict__ xb, const int* __restrict__ bstart,
        const uint32* __restrict__ eb,
        const uint32* __restrict__ WTmb, const float* __restrict__ bm,
        const uint32* __restrict__ WTub, const float* __restrict__ bu,
        float* __restrict__ out, int N_) {
    __shared__ float acc[RPB][D];    // 8 KB aggregated sums
    __shared__ float o_lds[RPB][D];  // 8 KB intermediate
    __shared__ int degl[RPB];

    const int tid  = threadIdx.x;
    const int lane = tid & 63;
    const int wv   = tid >> 6;

    for (int i = tid; i < RPB * D; i += 256) ((float*)acc)[i] = 0.f;
    if (tid < RPB) degl[tid] = 0;
    __syncthreads();

    const int s = bstart[blockIdx.x];
    const int e = bstart[blockIdx.x + 1];

    // ---- gather: each wave takes 64-edge chunks, strided by 256 ----
    for (int ii = s + wv * 64; ii < e; ii += 256) {
        int m = min(64, e - ii);
        uint32 v_l = (lane < m) ? eb[ii + lane] : 0;
        if (lane < m) atomicAdd(&degl[(v_l >> 16) & 15], 1);
        int t = 0;
        for (; t + 8 <= m; t += 8) {
            uint32 e0 = __builtin_amdgcn_readlane(v_l, t + 0);
            uint32 e1 = __builtin_amdgcn_readlane(v_l, t + 1);
            uint32 e2 = __builtin_amdgcn_readlane(v_l, t + 2);
            uint32 e3 = __builtin_amdgcn_readlane(v_l, t + 3);
            uint32 e4 = __builtin_amdgcn_readlane(v_l, t + 4);
            uint32 e5 = __builtin_amdgcn_readlane(v_l, t + 5);
            uint32 e6 = __builtin_amdgcn_readlane(v_l, t + 6);
            uint32 e7 = __builtin_amdgcn_readlane(v_l, t + 7);
            uint32 v0 = xb[((e0 & 0xffffu) << 6) + lane];
            uint32 v1 = xb[((e1 & 0xffffu) << 6) + lane];
            uint32 v2 = xb[((e2 & 0xffffu) << 6) + lane];
            uint32 v3 = xb[((e3 & 0xffffu) << 6) + lane];
            uint32 v4 = xb[((e4 & 0xffffu) << 6) + lane];
            uint32 v5 = xb[((e5 & 0xffffu) << 6) + lane];
            uint32 v6 = xb[((e6 & 0xffffu) << 6) + lane];
            uint32 v7 = xb[((e7 & 0xffffu) << 6) + lane];
            int r0 = (e0 >> 16) & 15, r1 = (e1 >> 16) & 15;
            int r2 = (e2 >> 16) & 15, r3 = (e3 >> 16) & 15;
            int r4 = (e4 >> 16) & 15, r5 = (e5 >> 16) & 15;
            int r6 = (e6 >> 16) & 15, r7 = (e7 >> 16) & 15;
            atomicAdd(&acc[r0][2 * lane], bfl(v0)); atomicAdd(&acc[r0][2 * lane + 1], bfh(v0));
            atomicAdd(&acc[r1][2 * lane], bfl(v1)); atomicAdd(&acc[r1][2 * lane + 1], bfh(v1));
            atomicAdd(&acc[r2][2 * lane], bfl(v2)); atomicAdd(&acc[r2][2 * lane + 1], bfh(v2));
            atomicAdd(&acc[r3][2 * lane], bfl(v3)); atomicAdd(&acc[r3][2 * lane + 1], bfh(v3));
            atomicAdd(&acc[r4][2 * lane], bfl(v4)); atomicAdd(&acc[r4][2 * lane + 1], bfh(v4));
            atomicAdd(&acc[r5][2 * lane], bfl(v5)); atomicAdd(&acc[r5][2 * lane + 1], bfh(v5));
            atomicAdd(&acc[r6][2 * lane], bfl(v6)); atomicAdd(&acc[r6][2 * lane + 1], bfh(v6));
            atomicAdd(&acc[r7][2 * lane], bfl(v7)); atomicAdd(&acc[r7][2 * lane + 1], bfh(v7));
        }
        for (; t < m; ++t) {
            uint32 ev = __builtin_amdgcn_readlane(v_l, t);
            uint32 v = xb[((ev & 0xffffu) << 6) + lane];
            int r = (ev >> 16) & 15;
            atomicAdd(&acc[r][2 * lane], bfl(v));
            atomicAdd(&acc[r][2 * lane + 1], bfh(v));
        }
    }
    __syncthreads();

    // ---- matvec phase: wave wv owns rows [wv*NPW, wv*NPW+NPW) ----
    const int f0 = lane, f1 = lane + 64;
    const int rbase = wv * NPW;

    float acc0[NPW], acc1[NPW];
    #pragma unroll
    for (int i = 0; i < NPW; ++i) { acc0[i] = 0.f; acc1[i] = 0.f; }

    for (int k2 = 0; k2 < 64; k2 += 2) {
        uint32 wm00 = WTmb[k2 * D + f0];
        uint32 wm01 = WTmb[(k2 + 1) * D + f0];
        uint32 wm10 = WTmb[k2 * D + f1];
        uint32 wm11 = WTmb[(k2 + 1) * D + f1];
        float w00l = bfl(wm00), w00h = bfh(wm00), w01l = bfl(wm01), w01h = bfh(wm01);
        float w10l = bfl(wm10), w10h = bfh(wm10), w11l = bfl(wm11), w11h = bfh(wm11);
        #pragma unroll
        for (int i = 0; i < NPW; ++i) {
            float4 a4 = *(const float4*)&acc[rbase + i][2 * k2];
            acc0[i] += a4.x * w00l + a4.y * w00h + a4.z * w01l + a4.w * w01h;
            acc1[i] += a4.x * w10l + a4.y * w10h + a4.z * w11l + a4.w * w11h;
        }
    }

    float bm0 = bm[f0], bm1 = bm[f1];
    #pragma unroll
    for (int i = 0; i < NPW; ++i) {
        float cnt = (float)degl[rbase + i];
        float inv = 1.0f / (cnt + EPS);
        o_lds[rbase + i][f0] = (acc0[i] + cnt * bm0) * inv;
        o_lds[rbase + i][f1] = (acc1[i] + cnt * bm1) * inv;
    }
    __syncthreads();

    #pragma unroll
    for (int i = 0; i < NPW; ++i) { acc0[i] = 0.f; acc1[i] = 0.f; }

    for (int k2 = 0; k2 < 64; k2 += 2) {
        uint32 wu00 = WTub[k2 * D + f0];
        uint32 wu01 = WTub[(k2 + 1) * D + f0];
        uint32 wu10 = WTub[k2 * D + f1];
        uint32 wu11 = WTub[(k2 + 1) * D + f1];
        float w00l = bfl(wu00), w00h = bfh(wu00), w01l = bfl(wu01), w01h = bfh(wu01);
        float w10l = bfl(wu10), w10h = bfh(wu10), w11l = bfl(wu11), w11h = bfh(wu11);
        #pragma unroll
        for (int i = 0; i < NPW; ++i) {
            float4 a4 = *(const float4*)&o_lds[rbase + i][2 * k2];
            acc0[i] += a4.x * w00l + a4.y * w00h + a4.z * w01l + a4.w * w01h;
            acc1[i] += a4.x * w10l + a4.y * w10h + a4.z * w11l + a4.w * w11h;
        }
    }

    float bu0 = bu[f0], bu1 = bu[f1];
    #pragma unroll
    for (int i = 0; i < NPW; ++i) {
        int n = blockIdx.x * RPB + rbase + i;
        if (n >= N_) continue;
        float t0 = acc0[i] + bu0;
        float t1 = acc1[i] + bu1;
        float v = t0 * t0 + t1 * t1;
        #pragma unroll
        for (int o = 32; o > 0; o >>= 1) v += __shfl_xor(v, o);
        float scale = 1.0f / (sqrtf(v) + EPS);
        out[n * D + f0] = t0 * scale;
        out[n * D + f1] = t1 * scale;
    }
}

// ---------------- launch ----------------

extern "C" void kernel_launch(void* const* d_in, const int* in_sizes, int n_in,
                              void* d_out, int out_size, void* d_ws, size_t ws_size,
                              hipStream_t stream) {
    const float* x  = (const float*)d_in[0];
    const int*   ei = (const int*)d_in[1];
    const float* Wm = (const float*)d_in[2];
    const float* bm = (const float*)d_in[3];
    const float* Wu = (const float*)d_in[4];
    const float* bu = (const float*)d_in[5];
    float* out = (float*)d_out;

    const int N_ = in_sizes[0] / D;        // 10000
    const int E_ = in_sizes[1] / 2;        // 640000
    const int NX = N_ * (D / 2);           // packed x pairs
    const int NB = (N_ + RPB - 1) / RPB;   // 625 buckets

    int* bhist   = (int*)d_ws;                    // NB
    int* bcur    = bhist + NB;                    // NB
    int* bstart  = bcur + NB;                     // NB+1
    uint32* xb   = (uint32*)(bstart + NB + 1);    // N*64
    uint32* eb   = xb + NX;                       // E packed edges
    uint32* WTmb = eb + E_;                       // 64*128
    uint32* WTub = WTmb + 64 * D;                 // 64*128

    hipMemsetAsync(bhist, 0, 2 * (size_t)NB * sizeof(int), stream);

    k_prep<<<(NX + 255) / 256, 256, 0, stream>>>(x, xb, NX);
    k_wprep<<<(64 * D + 255) / 256, 256, 0, stream>>>(Wm, Wu, WTmb, WTub);

    int nplace = (E_ + EPB - 1) / EPB;   // 79
    k_bhist<<<nplace, 256, 0, stream>>>(ei, bhist, E_, NB);
    k_scan<<<1, 1024, 0, stream>>>(bhist, bstart, NB);
    k_bplace<<<nplace, 256, 0, stream>>>(ei, bstart, bcur, eb, E_, NB);

    k_fused<<<NB, 256, 0, stream>>>(xb, bstart, eb, WTmb, bm, WTub, bu, out, N_);
}

// Round 8
// 102.755 us; speedup vs baseline: 5.6719x; 5.6622x over previous
//
#include <hip/hip_runtime.h>
#include <hip/hip_bf16.h>

#define D 128            // D_IN == D_OUT == 128
#define RPB 16           // rows per bucket
#define NBMAX 640        // max buckets (N<=10240)
#define EPB 8192         // edges per block in hist/place
#define CAP 2048         // staged edges per bucket (mean 1024, sigma 32)
#define NPW 4            // rows per wave in matvec/gather phase
#define EPS 1e-8f

typedef unsigned int uint32;
typedef unsigned short uint16;

__device__ __forceinline__ uint32 f2bf_rne(float f) {
    uint32 u = __float_as_uint(f);
    return (u + 0x7fffu + ((u >> 16) & 1u)) >> 16;   // round-nearest-even
}
__device__ __forceinline__ float bfl(uint32 u) { return __uint_as_float(u << 16); }
__device__ __forceinline__ float bfh(uint32 u) { return __uint_as_float(u & 0xffff0000u); }

// ---------------- prep: bf16-pack x ----------------

__global__ void k_prep(const float* __restrict__ x, uint32* __restrict__ xb, int NX) {
    int i = blockIdx.x * blockDim.x + threadIdx.x;
    if (i < NX) {
        float2 f = ((const float2*)x)[i];
        xb[i] = f2bf_rne(f.x) | (f2bf_rne(f.y) << 16);
    }
}

// ---------------- W transpose + bf16 pack ----------------

__global__ void k_wprep(const float* __restrict__ Wm, const float* __restrict__ Wu,
                        uint32* __restrict__ WTmb, uint32* __restrict__ WTub) {
    int i = blockIdx.x * blockDim.x + threadIdx.x;   // 64*128 threads
    if (i >= 64 * 128) return;
    int k2 = i >> 7, f = i & 127;
    WTmb[i] = f2bf_rne(Wm[f * D + 2 * k2]) | (f2bf_rne(Wm[f * D + 2 * k2 + 1]) << 16);
    WTub[i] = f2bf_rne(Wu[f * D + 2 * k2]) | (f2bf_rne(Wu[f * D + 2 * k2 + 1]) << 16);
}

// ---------------- bucket histogram (LDS pre-aggregated) ----------------

__global__ __launch_bounds__(256) void k_bhist(const int* __restrict__ ei,
                                               int* __restrict__ bhist, int E_, int NB) {
    __shared__ int h[NBMAX];
    for (int i = threadIdx.x; i < NB; i += 256) h[i] = 0;
    __syncthreads();
    int base = blockIdx.x * EPB;
    int hi = min(base + EPB, E_);
    for (int i = base + threadIdx.x; i < hi; i += 256)
        atomicAdd(&h[ei[i] >> 4], 1);
    __syncthreads();
    for (int i = threadIdx.x; i < NB; i += 256)
        if (h[i]) atomicAdd(&bhist[i], h[i]);
}

// ---------------- scan ----------------

__global__ void k_scan(const int* __restrict__ deg, int* __restrict__ starts, int N_) {
    __shared__ int part[1024];
    int t = threadIdx.x;
    int chunk = (N_ + 1023) / 1024;
    int s = t * chunk;
    int e = min(N_, s + chunk);
    int sum = 0;
    for (int i = s; i < e; ++i) sum += deg[i];
    part[t] = sum;
    __syncthreads();
    for (int off = 1; off < 1024; off <<= 1) {
        int u = (t >= off) ? part[t - off] : 0;
        __syncthreads();
        part[t] += u;
        __syncthreads();
    }
    int run = part[t] - sum;
    for (int i = s; i < e; ++i) { starts[i] = run; run += deg[i]; }
    if (t == 1023) starts[N_] = part[1023];
}

// ---------------- place: block-local counting sort by bucket ----------------

__global__ __launch_bounds__(256) void k_bplace(
        const int* __restrict__ ei, const int* __restrict__ bstart,
        int* __restrict__ bcur, uint32* __restrict__ eb, int E_, int NB) {
    __shared__ int h[NBMAX];
    __shared__ int off[NBMAX];
    __shared__ int bias[NBMAX];
    __shared__ uint32 stg[EPB];

    const int tid = threadIdx.x;
    const int base = blockIdx.x * EPB;
    const int nE = min(EPB, E_ - base);

    for (int i = tid; i < NB; i += 256) h[i] = 0;
    __syncthreads();

    for (int i = tid; i < nE; i += 256)
        atomicAdd(&h[ei[base + i] >> 4], 1);
    __syncthreads();

    if (tid < 64) {
        int b0 = tid * 10;
        int loc[10];
        int lsum = 0;
        #pragma unroll
        for (int j = 0; j < 10; ++j) {
            int b = b0 + j;
            int v = (b < NB) ? h[b] : 0;
            loc[j] = lsum;
            lsum += v;
        }
        int run = lsum;
        #pragma unroll
        for (int o = 1; o < 64; o <<= 1) {
            int u = __shfl_up(run, o);
            if (tid >= o) run += u;
        }
        int excl = run - lsum;
        #pragma unroll
        for (int j = 0; j < 10; ++j) {
            int b = b0 + j;
            if (b < NB) off[b] = excl + loc[j];
        }
    }
    __syncthreads();

    for (int b = tid; b < NB; b += 256) {
        int c = h[b];
        if (c) {
            int g = atomicAdd(&bcur[b], c);
            bias[b] = (bstart[b] + g) - off[b];
        }
    }
    __syncthreads();

    for (int i = tid; i < nE; i += 256) {
        int r = ei[base + i];
        int c = ei[E_ + base + i];
        int b = r >> 4;
        int p = atomicAdd(&off[b], 1);
        stg[p] = ((uint32)r << 16) | (uint32)c;
    }
    __syncthreads();

    for (int i = tid; i < nE; i += 256) {
        uint32 v = stg[i];
        int b = v >> 20;
        eb[bias[b] + i] = v;
    }
}

// ---------------- fused: in-block row sort + register gather + matvecs --------
// one block per bucket (16 rows); 256 threads = 4 waves; wave owns 4 rows

__global__ __launch_bounds__(256) void k_fused(
        const uint32* __restrict__ xb, const int* __restrict__ bstart,
        const uint32* __restrict__ eb,
        const uint32* __restrict__ WTmb, const float* __restrict__ bm,
        const uint32* __restrict__ WTub, const float* __restrict__ bu,
        float* __restrict__ out, int N_) {
    __shared__ float a_lds[RPB][D];     // 8 KB aggregated sums
    __shared__ float o_lds[RPB][D];     // 8 KB intermediate
    __shared__ uint16 stg[CAP];         // 4 KB cols sorted by row
    __shared__ int hist16[RPB], cur16[RPB], rst[RPB], dcnt[RPB];

    const int tid  = threadIdx.x;
    const int lane = tid & 63;
    const int wv   = tid >> 6;

    for (int i = tid; i < RPB * D; i += 256) ((float*)a_lds)[i] = 0.f;
    if (tid < RPB) { hist16[tid] = 0; cur16[tid] = 0; }
    __syncthreads();

    const int s    = bstart[blockIdx.x];
    const int cnt  = bstart[blockIdx.x + 1] - s;
    const int cntc = min(cnt, CAP);

    // pass A: row histogram of staged range
    for (int i = tid; i < cntc; i += 256)
        atomicAdd(&hist16[(eb[s + i] >> 16) & 15], 1);
    __syncthreads();
    if (tid == 0) {
        int run = 0;
        #pragma unroll
        for (int r = 0; r < RPB; ++r) { rst[r] = run; run += hist16[r]; dcnt[r] = hist16[r]; }
    }
    __syncthreads();

    // pass B: scatter cols into row-sorted staging
    for (int i = tid; i < cntc; i += 256) {
        uint32 v = eb[s + i];
        int r = (v >> 16) & 15;
        int p = rst[r] + atomicAdd(&cur16[r], 1);
        stg[p] = (uint16)(v & 0xffffu);
    }
    // overflow path (cnt > CAP: ~32 sigma event, never taken; correct + slow)
    for (int ii = cntc + wv * 64; ii < cnt; ii += 256) {
        int m = min(64, cnt - ii);
        uint32 v_l = (lane < m) ? eb[s + ii + lane] : 0;
        if (lane < m) atomicAdd(&dcnt[(v_l >> 16) & 15], 1);
        for (int t = 0; t < m; ++t) {
            uint32 ev = __builtin_amdgcn_readlane(v_l, t);
            uint32 v = xb[((ev & 0xffffu) << 6) + lane];
            int r = (ev >> 16) & 15;
            atomicAdd(&a_lds[r][2 * lane], bfl(v));
            atomicAdd(&a_lds[r][2 * lane + 1], bfh(v));
        }
    }
    __syncthreads();

    // ---- register gather: wave wv owns rows [wv*NPW, wv*NPW+NPW) ----
    const int rbase = wv * NPW;
    for (int j = 0; j < NPW; ++j) {
        int r = rbase + j;
        int lo = rst[r];
        int hi = lo + hist16[r];
        float ax0 = 0.f, ay0 = 0.f, ax1 = 0.f, ay1 = 0.f;
        for (int ii = lo; ii < hi; ii += 64) {
            int m = min(64, hi - ii);
            int c_l = (lane < m) ? (int)stg[ii + lane] : 0;
            int t = 0;
            for (; t + 8 <= m; t += 8) {
                int c0 = __builtin_amdgcn_readlane(c_l, t + 0);
                int c1 = __builtin_amdgcn_readlane(c_l, t + 1);
                int c2 = __builtin_amdgcn_readlane(c_l, t + 2);
                int c3 = __builtin_amdgcn_readlane(c_l, t + 3);
                int c4 = __builtin_amdgcn_readlane(c_l, t + 4);
                int c5 = __builtin_amdgcn_readlane(c_l, t + 5);
                int c6 = __builtin_amdgcn_readlane(c_l, t + 6);
                int c7 = __builtin_amdgcn_readlane(c_l, t + 7);
                uint32 v0 = xb[(c0 << 6) + lane];
                uint32 v1 = xb[(c1 << 6) + lane];
                uint32 v2 = xb[(c2 << 6) + lane];
                uint32 v3 = xb[(c3 << 6) + lane];
                uint32 v4 = xb[(c4 << 6) + lane];
                uint32 v5 = xb[(c5 << 6) + lane];
                uint32 v6 = xb[(c6 << 6) + lane];
                uint32 v7 = xb[(c7 << 6) + lane];
                ax0 += bfl(v0); ay0 += bfh(v0);
                ax1 += bfl(v1); ay1 += bfh(v1);
                ax0 += bfl(v2); ay0 += bfh(v2);
                ax1 += bfl(v3); ay1 += bfh(v3);
                ax0 += bfl(v4); ay0 += bfh(v4);
                ax1 += bfl(v5); ay1 += bfh(v5);
                ax0 += bfl(v6); ay0 += bfh(v6);
                ax1 += bfl(v7); ay1 += bfh(v7);
            }
            for (; t < m; ++t) {
                int c = __builtin_amdgcn_readlane(c_l, t);
                uint32 v = xb[(c << 6) + lane];
                ax0 += bfl(v); ay0 += bfh(v);
            }
        }
        atomicAdd(&a_lds[r][2 * lane],     ax0 + ax1);
        atomicAdd(&a_lds[r][2 * lane + 1], ay0 + ay1);
    }
    __syncthreads();

    // ---- matvec 1: out1 = (agg @ Wm^T + deg*bm) / (deg+eps) ----
    const int f0 = lane, f1 = lane + 64;

    float acc0[NPW], acc1[NPW];
    #pragma unroll
    for (int i = 0; i < NPW; ++i) { acc0[i] = 0.f; acc1[i] = 0.f; }

    for (int k2 = 0; k2 < 64; k2 += 2) {
        uint32 wm00 = WTmb[k2 * D + f0];
        uint32 wm01 = WTmb[(k2 + 1) * D + f0];
        uint32 wm10 = WTmb[k2 * D + f1];
        uint32 wm11 = WTmb[(k2 + 1) * D + f1];
        float w00l = bfl(wm00), w00h = bfh(wm00), w01l = bfl(wm01), w01h = bfh(wm01);
        float w10l = bfl(wm10), w10h = bfh(wm10), w11l = bfl(wm11), w11h = bfh(wm11);
        #pragma unroll
        for (int i = 0; i < NPW; ++i) {
            float4 a4 = *(const float4*)&a_lds[rbase + i][2 * k2];
            acc0[i] += a4.x * w00l + a4.y * w00h + a4.z * w01l + a4.w * w01h;
            acc1[i] += a4.x * w10l + a4.y * w10h + a4.z * w11l + a4.w * w11h;
        }
    }

    float bm0 = bm[f0], bm1 = bm[f1];
    #pragma unroll
    for (int i = 0; i < NPW; ++i) {
        float cntf = (float)dcnt[rbase + i];
        float inv = 1.0f / (cntf + EPS);
        o_lds[rbase + i][f0] = (acc0[i] + cntf * bm0) * inv;
        o_lds[rbase + i][f1] = (acc1[i] + cntf * bm1) * inv;
    }
    __syncthreads();

    // ---- matvec 2: out2 = out1 @ Wu^T + bu ----
    #pragma unroll
    for (int i = 0; i < NPW; ++i) { acc0[i] = 0.f; acc1[i] = 0.f; }

    for (int k2 = 0; k2 < 64; k2 += 2) {
        uint32 wu00 = WTub[k2 * D + f0];
        uint32 wu01 = WTub[(k2 + 1) * D + f0];
        uint32 wu10 = WTub[k2 * D + f1];
        uint32 wu11 = WTub[(k2 + 1) * D + f1];
        float w00l = bfl(wu00), w00h = bfh(wu00), w01l = bfl(wu01), w01h = bfh(wu01);
        float w10l = bfl(wu10), w10h = bfh(wu10), w11l = bfl(wu11), w11h = bfh(wu11);
        #pragma unroll
        for (int i = 0; i < NPW; ++i) {
            float4 a4 = *(const float4*)&o_lds[rbase + i][2 * k2];
            acc0[i] += a4.x * w00l + a4.y * w00h + a4.z * w01l + a4.w * w01h;
            acc1[i] += a4.x * w10l + a4.y * w10h + a4.z * w11l + a4.w * w11h;
        }
    }

    float bu0 = bu[f0], bu1 = bu[f1];
    #pragma unroll
    for (int i = 0; i < NPW; ++i) {
        int n = blockIdx.x * RPB + rbase + i;
        if (n >= N_) continue;
        float t0 = acc0[i] + bu0;
        float t1 = acc1[i] + bu1;
        float v = t0 * t0 + t1 * t1;
        #pragma unroll
        for (int o = 32; o > 0; o >>= 1) v += __shfl_xor(v, o);
        float scale = 1.0f / (sqrtf(v) + EPS);
        out[n * D + f0] = t0 * scale;
        out[n * D + f1] = t1 * scale;
    }
}

// ---------------- launch ----------------

extern "C" void kernel_launch(void* const* d_in, const int* in_sizes, int n_in,
                              void* d_out, int out_size, void* d_ws, size_t ws_size,
                              hipStream_t stream) {
    const float* x  = (const float*)d_in[0];
    const int*   ei = (const int*)d_in[1];
    const float* Wm = (const float*)d_in[2];
    const float* bm = (const float*)d_in[3];
    const float* Wu = (const float*)d_in[4];
    const float* bu = (const float*)d_in[5];
    float* out = (float*)d_out;

    const int N_ = in_sizes[0] / D;        // 10000
    const int E_ = in_sizes[1] / 2;        // 640000
    const int NX = N_ * (D / 2);           // packed x pairs
    const int NB = (N_ + RPB - 1) / RPB;   // 625 buckets

    int* bhist   = (int*)d_ws;                    // NB
    int* bcur    = bhist + NB;                    // NB
    int* bstart  = bcur + NB;                     // NB+1
    uint32* xb   = (uint32*)(bstart + NB + 1);    // N*64
    uint32* eb   = xb + NX;                       // E packed edges
    uint32* WTmb = eb + E_;                       // 64*128
    uint32* WTub = WTmb + 64 * D;                 // 64*128

    hipMemsetAsync(bhist, 0, 2 * (size_t)NB * sizeof(int), stream);

    k_prep<<<(NX + 255) / 256, 256, 0, stream>>>(x, xb, NX);
    k_wprep<<<(64 * D + 255) / 256, 256, 0, stream>>>(Wm, Wu, WTmb, WTub);

    int nplace = (E_ + EPB - 1) / EPB;   // 79
    k_bhist<<<nplace, 256, 0, stream>>>(ei, bhist, E_, NB);
    k_scan<<<1, 1024, 0, stream>>>(bhist, bstart, NB);
    k_bplace<<<nplace, 256, 0, stream>>>(ei, bstart, bcur, eb, E_, NB);

    k_fused<<<NB, 256, 0, stream>>>(xb, bstart, eb, WTmb, bm, WTub, bu, out, N_);
}

// Round 9
// 80.528 us; speedup vs baseline: 7.2374x; 1.2760x over previous
//
#include <hip/hip_runtime.h>
#include <hip/hip_bf16.h>

#define D 128            // D_IN == D_OUT == 128
#define RPB 8            // rows per bucket
#define NBMAX 1280       // max buckets (N<=10240)
#define EPB 8192         // edges per block in hist/place
#define CAP 1024         // staged edges per bucket (mean 512, ~22 sigma)
#define NPW 2            // rows per wave (4 waves x 2 = 8 rows)
#define EPS 1e-8f

typedef unsigned int uint32;
typedef unsigned short uint16;

__device__ __forceinline__ uint32 f2bf_rne(float f) {
    uint32 u = __float_as_uint(f);
    return (u + 0x7fffu + ((u >> 16) & 1u)) >> 16;   // round-nearest-even
}
__device__ __forceinline__ float bfl(uint32 u) { return __uint_as_float(u << 16); }
__device__ __forceinline__ float bfh(uint32 u) { return __uint_as_float(u & 0xffff0000u); }

// -------- fused prep: xb pack + W pack + bucket histogram (first 79 blocks) ----
// xb[c*64 + j] packs features (j, j+64) of node c

__global__ __launch_bounds__(256) void k_prep_all(
        const float* __restrict__ x, const int* __restrict__ ei,
        const float* __restrict__ Wm, const float* __restrict__ Wu,
        uint32* __restrict__ xb, uint32* __restrict__ WTmb, uint32* __restrict__ WTub,
        int* __restrict__ bhist, int E_, int NX, int NB) {
    __shared__ int h[NBMAX];
    const int i = blockIdx.x * 256 + threadIdx.x;

    if (i < NX) {
        int c = i >> 6, j = i & 63;
        float lo = x[c * D + j];
        float hi = x[c * D + j + 64];
        xb[i] = f2bf_rne(lo) | (f2bf_rne(hi) << 16);
    }
    if (i < 64 * D) {
        int k2 = i >> 7, f = i & 127;
        WTmb[i] = f2bf_rne(Wm[f * D + 2 * k2]) | (f2bf_rne(Wm[f * D + 2 * k2 + 1]) << 16);
        WTub[i] = f2bf_rne(Wu[f * D + 2 * k2]) | (f2bf_rne(Wu[f * D + 2 * k2 + 1]) << 16);
    }

    // histogram: first ceil(E/EPB) blocks each own an EPB chunk
    int base = blockIdx.x * EPB;
    if (base < E_) {
        for (int b = threadIdx.x; b < NB; b += 256) h[b] = 0;
        __syncthreads();
        int hi2 = min(base + EPB, E_);
        for (int e = base + threadIdx.x; e < hi2; e += 256)
            atomicAdd(&h[ei[e] >> 3], 1);
        __syncthreads();
        for (int b = threadIdx.x; b < NB; b += 256)
            if (h[b]) atomicAdd(&bhist[b], h[b]);
    }
}

// ---------------- scan ----------------

__global__ void k_scan(const int* __restrict__ deg, int* __restrict__ starts, int N_) {
    __shared__ int part[1024];
    int t = threadIdx.x;
    int chunk = (N_ + 1023) / 1024;
    int s = t * chunk;
    int e = min(N_, s + chunk);
    int sum = 0;
    for (int i = s; i < e; ++i) sum += deg[i];
    part[t] = sum;
    __syncthreads();
    for (int off = 1; off < 1024; off <<= 1) {
        int u = (t >= off) ? part[t - off] : 0;
        __syncthreads();
        part[t] += u;
        __syncthreads();
    }
    int run = part[t] - sum;
    for (int i = s; i < e; ++i) { starts[i] = run; run += deg[i]; }
    if (t == 1023) starts[N_] = part[1023];
}

// ---------------- place: block-local counting sort by bucket ----------------

__global__ __launch_bounds__(512) void k_bplace(
        const int* __restrict__ ei, const int* __restrict__ bstart,
        int* __restrict__ bcur, uint32* __restrict__ eb, int E_, int NB) {
    __shared__ int h[NBMAX];
    __shared__ int off[NBMAX];
    __shared__ int bias[NBMAX];
    __shared__ uint32 stg[EPB];

    const int tid = threadIdx.x;
    const int base = blockIdx.x * EPB;
    const int nE = min(EPB, E_ - base);

    for (int i = tid; i < NB; i += 512) h[i] = 0;
    __syncthreads();

    for (int i = tid; i < nE; i += 512)
        atomicAdd(&h[ei[base + i] >> 3], 1);
    __syncthreads();

    if (tid < 64) {
        int b0 = tid * 20;
        int loc[20];
        int lsum = 0;
        #pragma unroll
        for (int j = 0; j < 20; ++j) {
            int b = b0 + j;
            int v = (b < NB) ? h[b] : 0;
            loc[j] = lsum;
            lsum += v;
        }
        int run = lsum;
        #pragma unroll
        for (int o = 1; o < 64; o <<= 1) {
            int u = __shfl_up(run, o);
            if (tid >= o) run += u;
        }
        int excl = run - lsum;
        #pragma unroll
        for (int j = 0; j < 20; ++j) {
            int b = b0 + j;
            if (b < NB) off[b] = excl + loc[j];
        }
    }
    __syncthreads();

    for (int b = tid; b < NB; b += 512) {
        int c = h[b];
        if (c) {
            int g = atomicAdd(&bcur[b], c);
            bias[b] = (bstart[b] + g) - off[b];
        }
    }
    __syncthreads();

    for (int i = tid; i < nE; i += 512) {
        int r = ei[base + i];
        int c = ei[E_ + base + i];
        int b = r >> 3;
        int p = atomicAdd(&off[b], 1);
        stg[p] = ((uint32)r << 16) | (uint32)c;
    }
    __syncthreads();

    for (int i = tid; i < nE; i += 512) {
        uint32 v = stg[i];
        int b = v >> 19;                  // row = v>>16, bucket = row>>3
        eb[bias[b] + i] = v;
    }
}

// ---------------- fused: in-block row sort + register gather + matvecs --------
// one block per bucket (8 rows); 256 threads = 4 waves; wave owns 2 rows

__global__ __launch_bounds__(256) void k_fused(
        const uint32* __restrict__ xb, const int* __restrict__ bstart,
        const uint32* __restrict__ eb,
        const uint32* __restrict__ WTmb, const float* __restrict__ bm,
        const uint32* __restrict__ WTub, const float* __restrict__ bu,
        float* __restrict__ out, int N_) {
    __shared__ float a_lds[RPB][D];     // 4 KB aggregated sums
    __shared__ float o_lds[RPB][D];     // 4 KB intermediate
    __shared__ uint32 ebl[CAP];         // 4 KB edge cache
    __shared__ uint16 stg[CAP];         // 2 KB cols sorted by row
    __shared__ int hist8[RPB], cur8[RPB], rst[RPB], dcnt[RPB];

    const int tid  = threadIdx.x;
    const int lane = tid & 63;
    const int wv   = tid >> 6;

    for (int i = tid; i < RPB * D; i += 256) ((float*)a_lds)[i] = 0.f;
    if (tid < RPB) { hist8[tid] = 0; cur8[tid] = 0; }
    __syncthreads();

    const int s    = bstart[blockIdx.x];
    const int cnt  = bstart[blockIdx.x + 1] - s;
    const int cntc = min(cnt, CAP);

    // pass A: cache edges in LDS + row histogram
    for (int i = tid; i < cntc; i += 256) {
        uint32 v = eb[s + i];
        ebl[i] = v;
        atomicAdd(&hist8[(v >> 16) & 7], 1);
    }
    __syncthreads();
    if (tid == 0) {
        int run = 0;
        #pragma unroll
        for (int r = 0; r < RPB; ++r) { rst[r] = run; run += hist8[r]; dcnt[r] = hist8[r]; }
    }
    __syncthreads();

    // pass B: scatter cols into row-sorted staging (from LDS)
    for (int i = tid; i < cntc; i += 256) {
        uint32 v = ebl[i];
        int r = (v >> 16) & 7;
        int p = rst[r] + atomicAdd(&cur8[r], 1);
        stg[p] = (uint16)(v & 0xffffu);
    }
    // overflow path (cnt > CAP: ~22 sigma, never taken; correct + slow)
    for (int ii = cntc + wv * 64; ii < cnt; ii += 256) {
        int m = min(64, cnt - ii);
        uint32 v_l = (lane < m) ? eb[s + ii + lane] : 0;
        if (lane < m) atomicAdd(&dcnt[(v_l >> 16) & 7], 1);
        for (int t = 0; t < m; ++t) {
            uint32 ev = __builtin_amdgcn_readlane(v_l, t);
            uint32 v = xb[((ev & 0xffffu) << 6) + lane];
            int r = (ev >> 16) & 7;
            atomicAdd(&a_lds[r][lane],      bfl(v));
            atomicAdd(&a_lds[r][lane + 64], bfh(v));
        }
    }
    __syncthreads();

    // ---- register gather: wave wv owns rows [wv*NPW, wv*NPW+NPW) ----
    const int rbase = wv * NPW;
    #pragma unroll
    for (int j = 0; j < NPW; ++j) {
        int r = rbase + j;
        int lo = rst[r];
        int hi = lo + hist8[r];
        float ax0 = 0.f, ay0 = 0.f, ax1 = 0.f, ay1 = 0.f;
        for (int ii = lo; ii < hi; ii += 64) {
            int m = min(64, hi - ii);
            int c_l = (lane < m) ? (int)stg[ii + lane] : 0;
            int t = 0;
            for (; t + 8 <= m; t += 8) {
                int c0 = __builtin_amdgcn_readlane(c_l, t + 0);
                int c1 = __builtin_amdgcn_readlane(c_l, t + 1);
                int c2 = __builtin_amdgcn_readlane(c_l, t + 2);
                int c3 = __builtin_amdgcn_readlane(c_l, t + 3);
                int c4 = __builtin_amdgcn_readlane(c_l, t + 4);
                int c5 = __builtin_amdgcn_readlane(c_l, t + 5);
                int c6 = __builtin_amdgcn_readlane(c_l, t + 6);
                int c7 = __builtin_amdgcn_readlane(c_l, t + 7);
                uint32 v0 = xb[(c0 << 6) + lane];
                uint32 v1 = xb[(c1 << 6) + lane];
                uint32 v2 = xb[(c2 << 6) + lane];
                uint32 v3 = xb[(c3 << 6) + lane];
                uint32 v4 = xb[(c4 << 6) + lane];
                uint32 v5 = xb[(c5 << 6) + lane];
                uint32 v6 = xb[(c6 << 6) + lane];
                uint32 v7 = xb[(c7 << 6) + lane];
                ax0 += bfl(v0); ay0 += bfh(v0);
                ax1 += bfl(v1); ay1 += bfh(v1);
                ax0 += bfl(v2); ay0 += bfh(v2);
                ax1 += bfl(v3); ay1 += bfh(v3);
                ax0 += bfl(v4); ay0 += bfh(v4);
                ax1 += bfl(v5); ay1 += bfh(v5);
                ax0 += bfl(v6); ay0 += bfh(v6);
                ax1 += bfl(v7); ay1 += bfh(v7);
            }
            for (; t < m; ++t) {
                int c = __builtin_amdgcn_readlane(c_l, t);
                uint32 v = xb[(c << 6) + lane];
                ax0 += bfl(v); ay0 += bfh(v);
            }
        }
        a_lds[r][lane]      += ax0 + ax1;   // exclusive row per wave: plain add
        a_lds[r][lane + 64] += ay0 + ay1;
    }
    __syncthreads();

    // ---- matvec 1: out1 = (agg @ Wm^T + deg*bm) / (deg+eps) ----
    const int f0 = lane, f1 = lane + 64;

    float acc0[NPW], acc1[NPW];
    #pragma unroll
    for (int i = 0; i < NPW; ++i) { acc0[i] = 0.f; acc1[i] = 0.f; }

    for (int k2 = 0; k2 < 64; k2 += 2) {
        uint32 wm00 = WTmb[k2 * D + f0];
        uint32 wm01 = WTmb[(k2 + 1) * D + f0];
        uint32 wm10 = WTmb[k2 * D + f1];
        uint32 wm11 = WTmb[(k2 + 1) * D + f1];
        float w00l = bfl(wm00), w00h = bfh(wm00), w01l = bfl(wm01), w01h = bfh(wm01);
        float w10l = bfl(wm10), w10h = bfh(wm10), w11l = bfl(wm11), w11h = bfh(wm11);
        #pragma unroll
        for (int i = 0; i < NPW; ++i) {
            float4 a4 = *(const float4*)&a_lds[rbase + i][2 * k2];
            acc0[i] += a4.x * w00l + a4.y * w00h + a4.z * w01l + a4.w * w01h;
            acc1[i] += a4.x * w10l + a4.y * w10h + a4.z * w11l + a4.w * w11h;
        }
    }

    float bm0 = bm[f0], bm1 = bm[f1];
    #pragma unroll
    for (int i = 0; i < NPW; ++i) {
        float cntf = (float)dcnt[rbase + i];
        float inv = 1.0f / (cntf + EPS);
        o_lds[rbase + i][f0] = (acc0[i] + cntf * bm0) * inv;
        o_lds[rbase + i][f1] = (acc1[i] + cntf * bm1) * inv;
    }
    __syncthreads();

    // ---- matvec 2: out2 = out1 @ Wu^T + bu ----
    #pragma unroll
    for (int i = 0; i < NPW; ++i) { acc0[i] = 0.f; acc1[i] = 0.f; }

    for (int k2 = 0; k2 < 64; k2 += 2) {
        uint32 wu00 = WTub[k2 * D + f0];
        uint32 wu01 = WTub[(k2 + 1) * D + f0];
        uint32 wu10 = WTub[k2 * D + f1];
        uint32 wu11 = WTub[(k2 + 1) * D + f1];
        float w00l = bfl(wu00), w00h = bfh(wu00), w01l = bfl(wu01), w01h = bfh(wu01);
        float w10l = bfl(wu10), w10h = bfh(wu10), w11l = bfl(wu11), w11h = bfh(wu11);
        #pragma unroll
        for (int i = 0; i < NPW; ++i) {
            float4 a4 = *(const float4*)&o_lds[rbase + i][2 * k2];
            acc0[i] += a4.x * w00l + a4.y * w00h + a4.z * w01l + a4.w * w01h;
            acc1[i] += a4.x * w10l + a4.y * w10h + a4.z * w11l + a4.w * w11h;
        }
    }

    float bu0 = bu[f0], bu1 = bu[f1];
    #pragma unroll
    for (int i = 0; i < NPW; ++i) {
        int n = blockIdx.x * RPB + rbase + i;
        if (n >= N_) continue;
        float t0 = acc0[i] + bu0;
        float t1 = acc1[i] + bu1;
        float v = t0 * t0 + t1 * t1;
        #pragma unroll
        for (int o = 32; o > 0; o >>= 1) v += __shfl_xor(v, o);
        float scale = 1.0f / (sqrtf(v) + EPS);
        out[n * D + f0] = t0 * scale;
        out[n * D + f1] = t1 * scale;
    }
}

// ---------------- launch ----------------

extern "C" void kernel_launch(void* const* d_in, const int* in_sizes, int n_in,
                              void* d_out, int out_size, void* d_ws, size_t ws_size,
                              hipStream_t stream) {
    const float* x  = (const float*)d_in[0];
    const int*   ei = (const int*)d_in[1];
    const float* Wm = (const float*)d_in[2];
    const float* bm = (const float*)d_in[3];
    const float* Wu = (const float*)d_in[4];
    const float* bu = (const float*)d_in[5];
    float* out = (float*)d_out;

    const int N_ = in_sizes[0] / D;        // 10000
    const int E_ = in_sizes[1] / 2;        // 640000
    const int NX = N_ * (D / 2);           // packed x pairs
    const int NB = (N_ + RPB - 1) / RPB;   // 1250 buckets

    int* bhist   = (int*)d_ws;                    // NB
    int* bcur    = bhist + NB;                    // NB
    int* bstart  = bcur + NB;                     // NB+1
    uint32* xb   = (uint32*)(bstart + NB + 1);    // N*64
    uint32* eb   = xb + NX;                       // E packed edges
    uint32* WTmb = eb + E_;                       // 64*128
    uint32* WTub = WTmb + 64 * D;                 // 64*128

    hipMemsetAsync(bhist, 0, 2 * (size_t)NB * sizeof(int), stream);

    int pgrid = (max(NX, E_) + 255) / 256;   // 2500 (hist handled by first 79)
    k_prep_all<<<pgrid, 256, 0, stream>>>(x, ei, Wm, Wu, xb, WTmb, WTub, bhist, E_, NX, NB);
    k_scan<<<1, 1024, 0, stream>>>(bhist, bstart, NB);

    int nplace = (E_ + EPB - 1) / EPB;   // 79
    k_bplace<<<nplace, 512, 0, stream>>>(ei, bstart, bcur, eb, E_, NB);

    k_fused<<<NB, 256, 0, stream>>>(xb, bstart, eb, WTmb, bm, WTub, bu, out, N_);
}